// Round 6
// baseline (258.780 us; speedup 1.0000x reference)
//
#include <hip/hip_runtime.h>
#include <hip/hip_bf16.h>

#define B_ 8
#define T_ 4096
#define D_ 512
#define L_ 128
#define H_ 8
#define Dh_ 64
#define Lh_ 16
#define M_ (B_*T_)          // 32768 rows
#define SCALE 0.125f        // rsqrt(Dh)

typedef __bf16 v8bf __attribute__((ext_vector_type(8)));
typedef float  v4f  __attribute__((ext_vector_type(4)));
typedef unsigned short u16;
typedef u16 v8u __attribute__((ext_vector_type(8)));

__device__ __forceinline__ float b2f(u16 h){
    unsigned int u = ((unsigned int)h) << 16;
    return __builtin_bit_cast(float, u);
}
__device__ __forceinline__ u16 f2bf(float f){
    unsigned int u = __builtin_bit_cast(unsigned int, f);
    u += 0x7FFFu + ((u >> 16) & 1u);   // RNE
    return (u16)(u >> 16);
}

// compiler-only memory fence (wave-internal DS ops are in-order in HW)
__device__ __forceinline__ void wave_fence() {
    asm volatile("" ::: "memory");
}

// drain this wave's outstanding global_load_lds before reading their LDS dest
#define DRAIN_GLDS() do {                                        \
    asm volatile("s_waitcnt vmcnt(0)" ::: "memory");             \
    __builtin_amdgcn_sched_barrier(0);                           \
} while (0)

// async global->LDS, 16B per lane; lds dest = wave-uniform base + lane*16
__device__ __forceinline__ void gload16(const u16* g, u16* l) {
    __builtin_amdgcn_global_load_lds(
        (const __attribute__((address_space(1))) unsigned int*)(g),
        (__attribute__((address_space(3))) unsigned int*)(l), 16, 0, 0);
}

// ---------------------------------------------------------------------------
// prep: one launch = X fp32->bf16 convert (blocks 0..8191) + 4 weight
// transposes fp32(rows x cols) -> bf16 (cols x rows) (blocks 8192..8831)
// ---------------------------------------------------------------------------
__global__ __launch_bounds__(256) void prep(
        const float* __restrict__ X,  const float* __restrict__ Wq,
        const float* __restrict__ Wk, const float* __restrict__ Wv,
        const float* __restrict__ Wo,
        u16* __restrict__ Xb, u16* __restrict__ WT, u16* __restrict__ OT)
{
    int bid = blockIdx.x;
    if (bid < 8192) {   // X convert: 8 elems / thread
        const size_t i = (size_t)bid * 256 + threadIdx.x;
        const float4* s = (const float4*)X + i * 2;
        float4 a = s[0], b = s[1];
        v8u o;
        o[0] = f2bf(a.x); o[1] = f2bf(a.y); o[2] = f2bf(a.z); o[3] = f2bf(a.w);
        o[4] = f2bf(b.x); o[5] = f2bf(b.y); o[6] = f2bf(b.z); o[7] = f2bf(b.w);
        *((v8u*)Xb + i) = o;
        return;
    }
    bid -= 8192;
    const float* src; u16* dst; int cols, bx, by;
    if (bid < 64)       { src = Wq; dst = WT;             cols = 128; bx = bid & 3;  by = bid >> 2; }
    else if (bid < 128) { src = Wk; dst = WT + 128 * 512; cols = 128; bid -= 64;  bx = bid & 3;  by = bid >> 2; }
    else if (bid < 384) { src = Wv; dst = WT + 256 * 512; cols = 512; bid -= 128; bx = bid & 15; by = bid >> 4; }
    else                { src = Wo; dst = OT;             cols = 512; bid -= 384; bx = bid & 15; by = bid >> 4; }
    __shared__ u16 tile[32][33];
    const int tx = threadIdx.x & 31, ty = threadIdx.x >> 5;
    const int c0 = bx * 32, r0 = by * 32;
    #pragma unroll
    for (int i = 0; i < 32; i += 8)
        tile[ty + i][tx] = f2bf(src[(size_t)(r0 + ty + i) * cols + c0 + tx]);
    __syncthreads();
    #pragma unroll
    for (int i = 0; i < 32; i += 8)
        dst[(size_t)(c0 + ty + i) * 512 + r0 + tx] = tile[tx][ty + i];
}

// ---------------------------------------------------------------------------
// P1/P5: MFMA bf16 GEMM, R4 structure (single-buffer, proven 45 µs):
// BK=64, global_load_lds width=16, XOR granule swizzle, 8-panel XCD grouping.
// MODE 0 (NY=6): col-block 0 = QS (softmax folded), 1 = KE=exp(K*s),
//   2..5 = V written CHUNK-TRANSPOSED to VTo[bh][c][d][t] via LDS bounce
//   (replaces the old V buffer; coalesced 128B stores).
// MODE 1 (NY=4): fp32 Out.
// ---------------------------------------------------------------------------
template<int MODE, int NY>
__global__ __launch_bounds__(256) void gemm_mfma(
        const u16* __restrict__ A, const u16* __restrict__ Bt,
        float* __restrict__ Qo, u16* __restrict__ KEo,
        u16* __restrict__ VTo, float* __restrict__ OutF)
{
    __shared__ __align__(16) union GS {
        struct { u16 As[128 * 64]; u16 Bs[128 * 64]; } s;  // row*64+(g^(row&7))*8
        u16 vt[128][136];                                  // V-epilogue bounce
    } smem;
    const int tid  = threadIdx.x;
    const int wave = tid >> 6, lane = tid & 63;
    const int wm = wave >> 1, wn = wave & 1;     // 2x2 waves, 64x64 each
    const int lm = lane & 15, quad = lane >> 4;

    // grid = 8 XCD * 4 groups * (8 panels * NY cols); panel-fastest in group
    const int bid = blockIdx.x;
    const int xcd = bid & 7, j = bid >> 3;
    const int grp = j / (8 * NY), r = j % (8 * NY);
    const int by  = r >> 3, pin = r & 7;
    const int bx  = xcd * 32 + grp * 8 + pin;
    const int gm0 = bx * 128, gn0 = by * 128;

    const int srow0 = wave * 32 + (lane >> 3);   // staging row, + r*8
    const int sg    = lane & 7;                  // staging granule position

    v4f acc[4][4];
    #pragma unroll
    for (int i = 0; i < 4; i++)
        #pragma unroll
        for (int j2 = 0; j2 < 4; j2++)
            acc[i][j2] = (v4f){0.f, 0.f, 0.f, 0.f};

    for (int kt = 0; kt < 8; ++kt) {
        const int k0 = kt * 64;
        #pragma unroll
        for (int rr = 0; rr < 4; ++rr) {
            const int row = srow0 + rr * 8;
            const int col = ((sg ^ (row & 7)) << 3) + k0;   // source k-granule
            gload16(&A [(size_t)(gm0 + row) * 512 + col], &smem.s.As[(wave * 4 + rr) * 512]);
            gload16(&Bt[(size_t)(gn0 + row) * 512 + col], &smem.s.Bs[(wave * 4 + rr) * 512]);
        }
        __syncthreads();
        v8bf af[2][4], bfr[2][4];
        #pragma unroll
        for (int ks = 0; ks < 2; ks++)
            #pragma unroll
            for (int mi = 0; mi < 4; mi++) {
                const int g  = ks * 4 + quad;
                const int ra = wm * 64 + mi * 16 + lm;
                const int rb = wn * 64 + mi * 16 + lm;
                af [ks][mi] = *(const v8bf*)&smem.s.As[ra * 64 + ((g ^ (ra & 7)) << 3)];
                bfr[ks][mi] = *(const v8bf*)&smem.s.Bs[rb * 64 + ((g ^ (rb & 7)) << 3)];
            }
        #pragma unroll
        for (int ks = 0; ks < 2; ks++)
            #pragma unroll
            for (int mi = 0; mi < 4; mi++)
                #pragma unroll
                for (int ni = 0; ni < 4; ni++)
                    acc[mi][ni] = __builtin_amdgcn_mfma_f32_16x16x32_bf16(
                                      af[ks][mi], bfr[ks][ni], acc[mi][ni], 0, 0, 0);
        __syncthreads();
    }

    if (MODE == 1) {
        #pragma unroll
        for (int mi = 0; mi < 4; mi++)
          #pragma unroll
          for (int ni = 0; ni < 4; ni++)
            #pragma unroll
            for (int i = 0; i < 4; i++) {
                int row = gm0 + wm * 64 + mi * 16 + quad * 4 + i;
                int col = gn0 + wn * 64 + ni * 16 + lm;
                OutF[(size_t)row * 512 + col] = acc[mi][ni][i];
            }
    } else if (gn0 == 0) {
        // Q block: fold the row-softmax. 16 lm lanes = one head's Lh=16.
        #pragma unroll
        for (int mi = 0; mi < 4; mi++)
          #pragma unroll
          for (int ni = 0; ni < 4; ni++)
            #pragma unroll
            for (int i = 0; i < 4; i++) {
                int row = gm0 + wm * 64 + mi * 16 + quad * 4 + i;
                int col = wn * 64 + ni * 16 + lm;
                float qv = acc[mi][ni][i] * SCALE;
                float m = qv;
                #pragma unroll
                for (int off = 1; off < 16; off <<= 1) m = fmaxf(m, __shfl_xor(m, off));
                float e = __expf(qv - m);
                float s = e;
                #pragma unroll
                for (int off = 1; off < 16; off <<= 1) s += __shfl_xor(s, off);
                Qo[(size_t)row * 128 + col] = e / s;
            }
    } else if (gn0 == 128) {
        #pragma unroll
        for (int mi = 0; mi < 4; mi++)
          #pragma unroll
          for (int ni = 0; ni < 4; ni++)
            #pragma unroll
            for (int i = 0; i < 4; i++) {
                int row = gm0 + wm * 64 + mi * 16 + quad * 4 + i;
                int col = wn * 64 + ni * 16 + lm;
                KEo[(size_t)row * 128 + col] = f2bf(__expf(acc[mi][ni][i] * SCALE));
            }
    } else {
        // V block: bounce through LDS, write chunk-transposed VT[bh][c][d][t].
        // Stage: vt[cloc][tloc]; 16 lanes write rows +272B (2-way, free).
        #pragma unroll
        for (int mi = 0; mi < 4; mi++)
          #pragma unroll
          for (int ni = 0; ni < 4; ni++)
            #pragma unroll
            for (int i = 0; i < 4; i++) {
                int cloc = wn * 64 + ni * 16 + lm;              // V col - (gn0-256)
                int tloc = wm * 64 + mi * 16 + quad * 4 + i;    // row - gm0
                smem.vt[cloc][tloc] = f2bf(acc[mi][ni][i]);
            }
        __syncthreads();
        const int b   = gm0 >> 12, tau0 = gm0 & 4095, c0 = tau0 >> 6;
        const int h0  = (gn0 - 256) >> 6;
        const int d   = tid & 63, cl_ = (tid >> 6) & 1, hl = tid >> 7;
        const int bh  = b * 8 + h0 + hl;
        u16* dst = VTo + (((size_t)bh * 64 + (c0 + cl_)) * 64 + d) * 64;
        const u16* srow = &smem.vt[hl * 64 + d][cl_ * 64];
        #pragma unroll
        for (int k = 0; k < 8; ++k)
            *(v8u*)(dst + k * 8) = *(const v8u*)(srow + k * 8);
    }
}

// ---------------------------------------------------------------------------
// P2a (MFMA): per chunk, one wave: M_c = KE^T(16x64) . V(64x64), lsum = KE^T.1
// V^T tile loaded with 8 gload16 (XOR-pre-swizzled source, rule-21 pair with
// the swizzled ds_read) — no VGPR round-trip, no scalar transpose.
// ---------------------------------------------------------------------------
__global__ __launch_bounds__(256, 2) void chunk_sums_mfma(
        const u16* __restrict__ KE, const u16* __restrict__ VTg,
        float* __restrict__ Mc, float* __restrict__ AB)
{
    struct CLDS { u16 KA[16][72]; u16 VT[64][64]; };
    __shared__ __align__(16) CLDS lds[4];
    const int tid = threadIdx.x, wave = tid >> 6, lane = tid & 63;
    const int lm = lane & 15, quad = lane >> 4;
    const int ch = blockIdx.x * 4 + wave;
    const int bh = ch >> 6, c = ch & 63, b = bh >> 3, h = bh & 7;
    const int t0 = b * T_ + c * 64;
    CLDS& L = lds[wave];

    {
        // V^T[d][t] -> LDS VT[d][(gt ^ (d&7)) granules], linear dest
        const u16* vsrc = VTg + ((size_t)bh * 64 + c) * 4096;
        #pragma unroll
        for (int k = 0; k < 8; ++k) {
            const int d = k * 8 + (lane >> 3);
            const int g = (lane & 7) ^ (lane >> 3);
            gload16(vsrc + d * 64 + g * 8, &L.VT[k * 8][0]);
        }
        const u16* kp = KE + (size_t)(t0 + lane) * L_ + h * Lh_;
        v8u k0 = *(const v8u*)kp, k1 = *(const v8u*)(kp + 8);
        #pragma unroll
        for (int l = 0; l < 8; l++) L.KA[l][lane]     = k0[l];
        #pragma unroll
        for (int l = 0; l < 8; l++) L.KA[l + 8][lane] = k1[l];
    }
    wave_fence();

    v8bf ka[2];
    #pragma unroll
    for (int ki = 0; ki < 2; ki++)
        ka[ki] = *(const v8bf*)&L.KA[lm][ki * 32 + quad * 8];

    v8u onesu;
    #pragma unroll
    for (int j = 0; j < 8; j++) onesu[j] = 0x3F80;
    v8bf ones = __builtin_bit_cast(v8bf, onesu);

    v4f accL = (v4f){0.f, 0.f, 0.f, 0.f};
    accL = __builtin_amdgcn_mfma_f32_16x16x32_bf16(ka[0], ones, accL, 0, 0, 0);
    accL = __builtin_amdgcn_mfma_f32_16x16x32_bf16(ka[1], ones, accL, 0, 0, 0);

    DRAIN_GLDS();   // VT ready (issued early; latency hidden under KA/lsum)

    v4f accM[4];
    #pragma unroll
    for (int nd = 0; nd < 4; nd++) accM[nd] = (v4f){0.f, 0.f, 0.f, 0.f};
    #pragma unroll
    for (int nd = 0; nd < 4; nd++)
        #pragma unroll
        for (int ki = 0; ki < 2; ki++) {
            const int row = nd * 16 + lm;
            v8bf vb = *(const v8bf*)&L.VT[row][(((ki * 4 + quad) ^ (lm & 7)) << 3)];
            accM[nd] = __builtin_amdgcn_mfma_f32_16x16x32_bf16(ka[ki], vb, accM[nd], 0, 0, 0);
        }

    float* mcb = Mc + (size_t)ch * 1024;
    #pragma unroll
    for (int nd = 0; nd < 4; nd++)
        #pragma unroll
        for (int i = 0; i < 4; i++)
            mcb[(quad * 4 + i) * 64 + nd * 16 + lm] = accM[nd][i];
    if (lm == 0) {
        #pragma unroll
        for (int i = 0; i < 4; i++) AB[ch * 16 + quad * 4 + i] = accL[i];
    }
}

// ---------------------------------------------------------------------------
// P2b: exclusive prefix over chunks; independent preloads, in-register scan.
// McB now written TRANSPOSED within each chunk block: pos d*16+l (so intra
// can gload16 a linear [d][l] tile).  Reads permuted (L2/L3-resident Mc).
// ---------------------------------------------------------------------------
__global__ __launch_bounds__(256) void chunk_prefix(
        const float* __restrict__ Mc, u16* __restrict__ McB,
        float* __restrict__ AB)
{
    const int bh = blockIdx.x >> 2, qq = blockIdx.x & 3;
    const int j = qq * 256 + threadIdx.x;            // output pos d*16+l
    const int iin = ((j & 15) << 6) + (j >> 4);      // input pos l*64+d
    const size_t bbase = (size_t)bh * 65536;
    float v[64];
    #pragma unroll
    for (int c = 0; c < 64; ++c) v[c] = Mc[bbase + (size_t)c * 1024 + iin];
    float run = 0.f;
    #pragma unroll
    for (int c = 0; c < 64; ++c) {
        McB[bbase + (size_t)c * 1024 + j] = f2bf(run);
        run += v[c];
    }
    if (qq == 0 && threadIdx.x < 16) {
        const int l = threadIdx.x;
        float a[64];
        #pragma unroll
        for (int c = 0; c < 64; ++c) a[c] = AB[(bh * 64 + c) * 16 + l];
        float r2 = 0.f;
        #pragma unroll
        for (int c = 0; c < 64; ++c) {
            AB[(bh * 64 + c) * 16 + l] = r2;
            r2 += a[c];
        }
    }
}

// ---------------------------------------------------------------------------
// P3 (MFMA): alpha = AB + tril.ke; qs = QS/alpha; P = QS.KE^T (masked);
// Y = QS.S_c + P.V.  V^T/KEO/ScT tiles via gload16 (issued at entry, drained
// before first use — latency hides under alpha/softmax).  B-operand column
// accesses are now vector reads (KEO[t][l], ScT[d][l]) instead of 32 scalar
// half-lane-idle LDS reads.
// ---------------------------------------------------------------------------
__global__ __launch_bounds__(256, 2) void intra_mfma(
        const float* __restrict__ QS, const u16* __restrict__ KE,
        const u16* __restrict__ VTg, const u16* __restrict__ McB,
        const float* __restrict__ AB, u16* __restrict__ Y)
{
    struct ILDS {
        union {
            struct { u16 KA[16][72]; u16 KEO[64][16]; u16 ScT[64][16]; u16 qs[64][40]; } s;
            u16 p[64][72];   // overlaps KA/KEO/ScT/qs-head: all consumed first
        } r;
        u16 VT[64][64];
    };
    __shared__ __align__(16) ILDS lds[4];
    const int tid = threadIdx.x, wave = tid >> 6, lane = tid & 63;
    const int lm = lane & 15, quad = lane >> 4;
    const int ch = blockIdx.x * 4 + wave;
    const int bh = ch >> 6, c = ch & 63, b = bh >> 3, h = bh & 7;
    const int t0 = b * T_ + c * 64;
    ILDS& L = lds[wave];

    {
        // async tiles first (12 gload16 in flight across alpha/softmax)
        const u16* vsrc = VTg + ((size_t)bh * 64 + c) * 4096;
        #pragma unroll
        for (int k = 0; k < 8; ++k) {
            const int d = k * 8 + (lane >> 3);
            const int g = (lane & 7) ^ (lane >> 3);
            gload16(vsrc + d * 64 + g * 8, &L.VT[k * 8][0]);
        }
        #pragma unroll
        for (int k = 0; k < 2; ++k) {
            const int slot = k * 64 + lane;
            gload16(KE + (size_t)(t0 + (slot >> 1)) * L_ + h * Lh_ + (slot & 1) * 8,
                    &L.r.s.KEO[k * 32][0]);
            gload16(McB + (size_t)ch * 1024 + slot * 8, &L.r.s.ScT[k * 32][0]);
        }
        const u16* kp = KE + (size_t)(t0 + lane) * L_ + h * Lh_;
        v8u k0 = *(const v8u*)kp, k1 = *(const v8u*)(kp + 8);
        #pragma unroll
        for (int l = 0; l < 8; l++) L.r.s.KA[l][lane]     = k0[l];
        #pragma unroll
        for (int l = 0; l < 8; l++) L.r.s.KA[l + 8][lane] = k1[l];
        v8u z8;
        #pragma unroll
        for (int j = 0; j < 8; j++) z8[j] = 0;
        *(v8u*)&L.r.s.qs[lane][16] = z8;
        *(v8u*)&L.r.s.qs[lane][24] = z8;
    }
    const float ab = AB[ch * 16 + lm];
    wave_fence();

    v4f acc_a[4];
    #pragma unroll
    for (int mi = 0; mi < 4; mi++) acc_a[mi] = (v4f){ab, ab, ab, ab};
    #pragma unroll
    for (int mi = 0; mi < 4; mi++)
        #pragma unroll
        for (int ki = 0; ki < 2; ki++) {
            if (ki == 1 && mi < 2) continue;
            v8u ta;
            #pragma unroll
            for (int j = 0; j < 8; j++)
                ta[j] = (ki * 32 + quad * 8 + j <= mi * 16 + lm) ? (u16)0x3F80 : (u16)0;
            v8bf kb = *(const v8bf*)&L.r.s.KA[lm][ki * 32 + quad * 8];
            acc_a[mi] = __builtin_amdgcn_mfma_f32_16x16x32_bf16(
                            __builtin_bit_cast(v8bf, ta), kb, acc_a[mi], 0, 0, 0);
        }

    #pragma unroll
    for (int mi = 0; mi < 4; mi++)
        #pragma unroll
        for (int i = 0; i < 4; i++) {
            int t = mi * 16 + quad * 4 + i;
            float qs = QS[(size_t)(t0 + t) * L_ + h * Lh_ + lm];
            L.r.s.qs[t][lm] = f2bf(qs / acc_a[mi][i]);
        }
    wave_fence();

    v8bf aq[4];
    #pragma unroll
    for (int mi = 0; mi < 4; mi++)
        aq[mi] = *(const v8bf*)&L.r.s.qs[mi * 16 + lm][quad * 8];

    DRAIN_GLDS();   // KEO / ScT / VT all landed

    v4f accP[4][4], accY[4][4];
    #pragma unroll
    for (int mi = 0; mi < 4; mi++)
        #pragma unroll
        for (int ni = 0; ni < 4; ni++) {
            accP[mi][ni] = (v4f){0.f, 0.f, 0.f, 0.f};
            accY[mi][ni] = (v4f){0.f, 0.f, 0.f, 0.f};
        }

    v8u zero8;
    #pragma unroll
    for (int j = 0; j < 8; j++) zero8[j] = 0;

    #pragma unroll
    for (int ni = 0; ni < 4; ni++) {
        v8bf kbf = (quad < 2)
            ? *(const v8bf*)&L.r.s.KEO[ni * 16 + lm][quad * 8]
            : __builtin_bit_cast(v8bf, zero8);
        #pragma unroll
        for (int mi = ni; mi < 4; mi++)
            accP[mi][ni] = __builtin_amdgcn_mfma_f32_16x16x32_bf16(
                               aq[mi], kbf, accP[mi][ni], 0, 0, 0);
    }
    #pragma unroll
    for (int nd = 0; nd < 4; nd++) {
        v8bf scf = (quad < 2)
            ? *(const v8bf*)&L.r.s.ScT[nd * 16 + lm][quad * 8]
            : __builtin_bit_cast(v8bf, zero8);
        #pragma unroll
        for (int mi = 0; mi < 4; mi++)
            accY[mi][nd] = __builtin_amdgcn_mfma_f32_16x16x32_bf16(
                               aq[mi], scf, accY[mi][nd], 0, 0, 0);
    }
    wave_fence();

    #pragma unroll
    for (int mi = 0; mi < 4; mi++)
        #pragma unroll
        for (int ni = 0; ni < 4; ni++)
            #pragma unroll
            for (int i = 0; i < 4; i++) {
                int t = mi * 16 + quad * 4 + i, tp = ni * 16 + lm;
                float pv = (ni < mi) ? accP[mi][ni][i]
                          : (ni == mi ? ((tp <= t) ? accP[mi][ni][i] : 0.f) : 0.f);
                L.r.p[t][tp] = f2bf(pv);
            }
    wave_fence();

    #pragma unroll
    for (int mi = 0; mi < 4; mi++)
        #pragma unroll
        for (int ki = 0; ki < 2; ki++) {
            if (ki == 1 && mi < 2) continue;
            v8bf pa = *(const v8bf*)&L.r.p[mi * 16 + lm][ki * 32 + quad * 8];
            #pragma unroll
            for (int nd = 0; nd < 4; nd++) {
                const int row = nd * 16 + lm;
                v8bf vb = *(const v8bf*)&L.VT[row][(((ki * 4 + quad) ^ (lm & 7)) << 3)];
                accY[mi][nd] = __builtin_amdgcn_mfma_f32_16x16x32_bf16(
                                   pa, vb, accY[mi][nd], 0, 0, 0);
            }
        }

    #pragma unroll
    for (int mi = 0; mi < 4; mi++)
        #pragma unroll
        for (int nd = 0; nd < 4; nd++)
            #pragma unroll
            for (int i = 0; i < 4; i++) {
                int t = mi * 16 + quad * 4 + i;
                Y[(((size_t)(c * 64 + t)) * 64 + bh) * 64 + nd * 16 + lm] =
                    f2bf(accY[mi][nd][i]);
            }
}

// ---------------------------------------------------------------------------
// P4: Z = Y^T.  Col-major LDS tile [dh][bh]; 4 tiles/block, one per wave.
// ---------------------------------------------------------------------------
__global__ __launch_bounds__(256) void transpose_Y(
        const u16* __restrict__ Y, u16* __restrict__ Z)
{
    __shared__ __align__(16) u16 tile[4][64][72];   // [wave][dh][bh]
    const int wave = threadIdx.x >> 6, t = threadIdx.x & 63;
    const int g = blockIdx.x * 4 + wave;
    u16 (*tl)[72] = tile[wave];
    const u16* yp = Y + (size_t)(g * 64 + t) * 64;
    #pragma unroll
    for (int seg = 0; seg < 8; ++seg) {
        v8u v = *(const v8u*)(yp + seg * 8);
        #pragma unroll
        for (int j = 0; j < 8; j++) tl[seg * 8 + j][t] = v[j];
    }
    wave_fence();
    const int cl = t & 7, dq = t >> 3;
    #pragma unroll
    for (int p = 0; p < 8; ++p) {
        const int dh = p * 8 + dq;
        v8u pk = *(const v8u*)&tl[dh][cl * 8];
        *(v8u*)&Z[(size_t)dh * 262144 + (size_t)g * 64 + cl * 8] = pk;
    }
}

// ---------------------------------------------------------------------------
extern "C" void kernel_launch(void* const* d_in, const int* in_sizes, int n_in,
                              void* d_out, int out_size, void* d_ws, size_t ws_size,
                              hipStream_t stream)
{
    (void)in_sizes; (void)n_in; (void)out_size; (void)ws_size;
    const float* X  = (const float*)d_in[0];
    const float* Wk = (const float*)d_in[1];   // dict order: X, Wk, Wq, Wv, o_proj
    const float* Wq = (const float*)d_in[2];
    const float* Wv = (const float*)d_in[3];
    const float* Wo = (const float*)d_in[4];
    float* Out = (float*)d_out;

    char* p = (char*)d_ws;
    auto alloc = [&](size_t bytes) { char* r = p; p += (bytes + 255) & ~(size_t)255; return r; };
    u16*   Xb  = (u16*)  alloc((size_t)M_ * 512 * 2);
    u16*   WT  = (u16*)  alloc((size_t)768 * 512 * 2);
    u16*   OT  = (u16*)  alloc((size_t)512 * 512 * 2);
    u16*   VTg = (u16*)  alloc((size_t)M_ * 512 * 2);     // V chunk-transposed
    float* Mc  = (float*)alloc((size_t)4096 * 1024 * 4);  // 16.78 MB
    float* AB  = (float*)alloc((size_t)4096 * 16 * 4);
    float* Q   = (float*)alloc((size_t)M_ * 128 * 4);     // QS (softmaxed), fp32
    u16*   KE  = (u16*)  alloc((size_t)M_ * 128 * 2);
    u16*   Y   = (u16*)  alloc((size_t)M_ * 512 * 2);
    u16*   Z   = (u16*)Mc;   // alias: Mc+AB+Q dead after intra; Z needs 33.5MB
    u16*   McB = (u16*)Xb;   // alias: Xb dead after gemm0; bf16 prefix (8.39MB)

    prep<<<8832, 256, 0, stream>>>(X, Wq, Wk, Wv, Wo, Xb, WT, OT);

    gemm_mfma<0, 6><<<1536, 256, 0, stream>>>(Xb, WT, Q, KE, VTg, nullptr);
    chunk_sums_mfma<<<1024, 256, 0, stream>>>(KE, VTg, Mc, AB);
    chunk_prefix   <<<256,  256, 0, stream>>>(Mc, McB, AB);
    intra_mfma     <<<1024, 256, 0, stream>>>(Q, KE, VTg, McB, AB, Y);
    transpose_Y    <<<1024, 256, 0, stream>>>(Y, Z);
    gemm_mfma<1, 4><<<1024, 256, 0, stream>>>(Z, OT, nullptr, nullptr, nullptr, Out);
}